// Round 5
// baseline (484.846 us; speedup 1.0000x reference)
//
#include <hip/hip_runtime.h>

#define N_NODES    100000
#define N_EDGES    1600000
#define NUM_REL    4
#define NUM_GRAPHS 256

constexpr int NR       = N_NODES * NUM_REL;   // 400000 segments
constexpr int NB       = (NR + 255) / 256;    // 1563 scan blocks
constexpr int SB_ITEMS = (NB + 255) / 256;    // 7 items/thread in scanB

// ---- monotonic float<->uint encoding for atomicMax on floats ----
__device__ __forceinline__ unsigned fenc(float f) {
    unsigned u = __float_as_uint(f);
    return (u & 0x80000000u) ? ~u : (u | 0x80000000u);
}
__device__ __forceinline__ float fdec(unsigned e) {
    return __uint_as_float((e & 0x80000000u) ? (e ^ 0x80000000u) : ~e);
}

__global__ void init_kernel(int* __restrict__ cnt, unsigned* __restrict__ pool) {
    int i = blockIdx.x * blockDim.x + threadIdx.x;
    if (i < NR) cnt[i] = 0;
    if (i < NUM_GRAPHS * 64) pool[i] = fenc(-INFINITY);
}

// convert fp32 features to fp16 storage
__global__ void convert_kernel(const float* __restrict__ xin, _Float16* __restrict__ xout,
                               int n) {
    int i = blockIdx.x * 256 + threadIdx.x;
    if (i < n) xout[i] = (_Float16)xin[i];
}

// count edges per (dst, rel) segment
__global__ void count_kernel(const int* __restrict__ dst, const int* __restrict__ etype,
                             int* __restrict__ cnt) {
    int e = blockIdx.x * 256 + threadIdx.x;
    if (e >= N_EDGES) return;
    atomicAdd(cnt + dst[e] * NUM_REL + etype[e], 1);
}

// per-block inclusive scan of cnt -> incl; block totals -> bsums
__global__ void scanA_kernel(const int* __restrict__ cnt, int* __restrict__ incl,
                             int* __restrict__ bsums) {
    __shared__ int sd[256];
    int t = threadIdx.x;
    int idx = blockIdx.x * 256 + t;
    sd[t] = (idx < NR) ? cnt[idx] : 0;
    __syncthreads();
#pragma unroll
    for (int off = 1; off < 256; off <<= 1) {
        int a = (t >= off) ? sd[t - off] : 0;
        __syncthreads();
        sd[t] += a;
        __syncthreads();
    }
    if (idx < NR) incl[idx] = sd[t];
    if (t == 255) bsums[blockIdx.x] = sd[255];
}

// single-block exclusive scan of the block sums
__global__ void scanB_kernel(const int* __restrict__ bsums, int* __restrict__ boffs) {
    __shared__ int sd[256];
    int t = threadIdx.x;
    int pre[SB_ITEMS];
    int run = 0;
#pragma unroll
    for (int k = 0; k < SB_ITEMS; ++k) {
        int ix = t * SB_ITEMS + k;
        pre[k] = run;
        run += (ix < NB) ? bsums[ix] : 0;
    }
    sd[t] = run;
    __syncthreads();
#pragma unroll
    for (int off = 1; off < 256; off <<= 1) {
        int a = (t >= off) ? sd[t - off] : 0;
        __syncthreads();
        sd[t] += a;
        __syncthreads();
    }
    int excl = sd[t] - run;
#pragma unroll
    for (int k = 0; k < SB_ITEMS; ++k) {
        int ix = t * SB_ITEMS + k;
        if (ix < NB) boffs[ix] = excl + pre[k];
    }
}

// finalize exclusive offsets in place over incl
__global__ void scanC_kernel(const int* __restrict__ cnt, int* __restrict__ offs_inout,
                             const int* __restrict__ boffs) {
    int idx = blockIdx.x * 256 + threadIdx.x;
    if (idx >= NR) return;
    offs_inout[idx] = boffs[idx >> 8] + offs_inout[idx] - cnt[idx];
}

// place src node ids into CSR slots; offs[seg] ends at segment END (= start + cnt)
__global__ void place_kernel(const int* __restrict__ src, const int* __restrict__ dst,
                             const int* __restrict__ etype, int* __restrict__ offs,
                             int* __restrict__ csr) {
    int e = blockIdx.x * 256 + threadIdx.x;
    if (e >= N_EDGES) return;
    int seg = dst[e] * NUM_REL + etype[e];
    int pos = atomicAdd(offs + seg, 1);
    csr[pos] = src[e];
}

// 8-way ILP gather of one segment: sum of x[csr[start..start+len)][i] (fp16 -> fp32)
template<int DIN>
__device__ __forceinline__ float gather_sum(const _Float16* __restrict__ x,
                                            const int* __restrict__ csr,
                                            int start, int len, int i) {
    float s0 = 0.f, s1 = 0.f, s2 = 0.f, s3 = 0.f;
    float s4 = 0.f, s5 = 0.f, s6 = 0.f, s7 = 0.f;
    for (int k = 0; k < len; k += 8) {
        int lim = len - k;                      // >=1
        int c[8];
#pragma unroll
        for (int m = 0; m < 8; ++m)
            c[m] = csr[start + (m < lim ? k + m : k)];
        float v[8];
#pragma unroll
        for (int m = 0; m < 8; ++m)
            v[m] = (float)x[(size_t)c[m] * DIN + i];
        if (0 < lim) s0 += v[0];
        if (1 < lim) s1 += v[1];
        if (2 < lim) s2 += v[2];
        if (3 < lim) s3 += v[3];
        if (4 < lim) s4 += v[4];
        if (5 < lim) s5 += v[5];
        if (6 < lim) s6 += v[6];
        if (7 < lim) s7 += v[7];
    }
    return ((s0 + s1) + (s2 + s3)) + ((s4 + s5) + (s6 + s7));
}

// fused per-node: gather per-relation means (CSR) -> LDS, then transform
// out = bias + x@root + sum_r mean_r @ W_r ; optional ReLU ; optional fused max-pool
// offsets[] holds segment END (start = offsets[seg] - cnt[seg]) after place_kernel.
template<int DIN, int DOUT, bool RELU, bool POOL>
__global__ __launch_bounds__(256)
void layer_kernel(const _Float16* __restrict__ x,
                  const int* __restrict__ csr,
                  const int* __restrict__ offsets,
                  const int* __restrict__ cnt,
                  const float* __restrict__ W,     // [R, DIN, DOUT]
                  const float* __restrict__ root,  // [DIN, DOUT]
                  const float* __restrict__ bias,  // [DOUT]
                  _Float16* __restrict__ hout,     // [N, DOUT] if !POOL
                  const int* __restrict__ batch,
                  unsigned* __restrict__ pool) {
    __shared__ float mean[4][NUM_REL][DIN];
    __shared__ float xrow[4][DIN];
    __shared__ float pval[4][64];
    __shared__ int   pg[4];
    __shared__ int   sameflag;

    const int w    = threadIdx.x >> 6;
    const int lane = threadIdx.x & 63;
    const int n    = blockIdx.x * 4 + w;   // 100000 = 4 * 25000, exact

    // ---- aggregation (gather, 8-way ILP) ----
    if constexpr (DIN == 16) {
        int r = lane >> 4, i = lane & 15;
        int seg = n * NUM_REL + r;
        int len = cnt[seg];
        int start = offsets[seg] - len;
        float s = (len > 0) ? gather_sum<16>(x, csr, start, len, i) : 0.f;
        mean[w][r][i] = s * (1.0f / fmaxf((float)len, 1.0f));
        if (r == 0) xrow[w][i] = (float)x[(size_t)n * DIN + i];
    } else { // DIN == 32
        int r2 = lane >> 5, i = lane & 31;
#pragma unroll
        for (int pass = 0; pass < 2; ++pass) {
            int r = pass * 2 + r2;
            int seg = n * NUM_REL + r;
            int len = cnt[seg];
            int start = offsets[seg] - len;
            float s = (len > 0) ? gather_sum<32>(x, csr, start, len, i) : 0.f;
            mean[w][r][i] = s * (1.0f / fmaxf((float)len, 1.0f));
        }
        if (lane < 32) xrow[w][lane] = (float)x[(size_t)n * DIN + lane];
    }
    __syncthreads();

    // ---- transform ----
    constexpr int Q = 64 / DOUT;      // 4, 2, 1
    const int j = lane % DOUT;
    const int q = lane / DOUT;
    float acc = 0.f;
    for (int t = q; t < NUM_REL + 1; t += Q) {
        if (t == 0) {
#pragma unroll
            for (int i = 0; i < DIN; ++i)
                acc = fmaf(xrow[w][i], root[i * DOUT + j], acc);
        } else {
            const int r = t - 1;
            const float* Wr = W + r * DIN * DOUT;
            const float* m = mean[w][r];
#pragma unroll
            for (int i = 0; i < DIN; ++i)
                acc = fmaf(m[i], Wr[i * DOUT + j], acc);
        }
    }
#pragma unroll
    for (int off = DOUT; off < 64; off <<= 1)
        acc += __shfl_xor(acc, off, 64);
    acc += bias[j];

    if constexpr (POOL) {
        // DOUT == 64: every lane holds channel j = lane
        pval[w][lane] = acc;
        if (lane == 0) pg[w] = batch[n];
        __syncthreads();
        if (threadIdx.x == 0)
            sameflag = (pg[0] == pg[1]) && (pg[0] == pg[2]) && (pg[0] == pg[3]);
        __syncthreads();
        if (sameflag) {
            if (w == 0) {
                float m0 = fmaxf(fmaxf(pval[0][lane], pval[1][lane]),
                                 fmaxf(pval[2][lane], pval[3][lane]));
                atomicMax(pool + pg[0] * 64 + lane, fenc(m0));
            }
        } else {
            atomicMax(pool + pg[w] * 64 + lane, fenc(pval[w][lane]));
        }
    } else {
        if (lane < DOUT) {
            float v = RELU ? fmaxf(acc, 0.f) : acc;
            hout[(size_t)n * DOUT + j] = (_Float16)v;
        }
    }
}

__global__ void decode_kernel(const unsigned* __restrict__ pool, float* __restrict__ out) {
    int i = blockIdx.x * blockDim.x + threadIdx.x;
    if (i < NUM_GRAPHS * 64) out[i] = fdec(pool[i]);
}

extern "C" void kernel_launch(void* const* d_in, const int* in_sizes, int n_in,
                              void* d_out, int out_size, void* d_ws, size_t ws_size,
                              hipStream_t stream) {
    const float* x     = (const float*)d_in[0];
    const int*   ei    = (const int*)d_in[1];
    const int*   etype = (const int*)d_in[2];
    const int*   batch = (const int*)d_in[3];
    const float* W1 = (const float*)d_in[4],  *root1 = (const float*)d_in[5],  *b1 = (const float*)d_in[6];
    const float* W2 = (const float*)d_in[7],  *root2 = (const float*)d_in[8],  *b2 = (const float*)d_in[9];
    const float* W3 = (const float*)d_in[10], *root3 = (const float*)d_in[11], *b3 = (const float*)d_in[12];
    float* out = (float*)d_out;

    const int* src = ei;
    const int* dst = ei + N_EDGES;

    // workspace layout, ~23 MB total
    int*       cnt   = (int*)d_ws;                   // NR
    int*       offs  = cnt + NR;                     // NR
    int*       bsums = offs + NR;                    // 2048
    int*       boffs = bsums + 2048;                 // 2048
    int*       csr   = boffs + 2048;                 // N_EDGES
    _Float16*  xh    = (_Float16*)(csr + N_EDGES);   // N*16
    _Float16*  h1    = xh + (size_t)N_NODES * 16;    // N*16
    _Float16*  h2    = h1 + (size_t)N_NODES * 16;    // N*32
    unsigned*  pool  = (unsigned*)(h2 + (size_t)N_NODES * 32); // 256*64

    const int BT = 256;
    const int gE = (N_EDGES + BT - 1) / BT;
    const int gI = (NR + BT - 1) / BT;
    const int gL = N_NODES / 4;

    init_kernel<<<gI, BT, 0, stream>>>(cnt, pool);
    convert_kernel<<<(N_NODES * 16 + BT - 1) / BT, BT, 0, stream>>>(x, xh, N_NODES * 16);
    count_kernel<<<gE, BT, 0, stream>>>(dst, etype, cnt);
    scanA_kernel<<<NB, BT, 0, stream>>>(cnt, offs, bsums);
    scanB_kernel<<<1, BT, 0, stream>>>(bsums, boffs);
    scanC_kernel<<<gI, BT, 0, stream>>>(cnt, offs, boffs);
    place_kernel<<<gE, BT, 0, stream>>>(src, dst, etype, offs, csr);

    layer_kernel<16, 16, true,  false><<<gL, BT, 0, stream>>>(
        xh, csr, offs, cnt, W1, root1, b1, h1, batch, pool);
    layer_kernel<16, 32, true,  false><<<gL, BT, 0, stream>>>(
        h1, csr, offs, cnt, W2, root2, b2, h2, batch, pool);
    layer_kernel<32, 64, false, true ><<<gL, BT, 0, stream>>>(
        h2, csr, offs, cnt, W3, root3, b3, nullptr, batch, pool);

    decode_kernel<<<(NUM_GRAPHS * 64 + BT - 1) / BT, BT, 0, stream>>>(pool, out);
}

// Round 6
// 464.852 us; speedup vs baseline: 1.0430x; 1.0430x over previous
//
#include <hip/hip_runtime.h>

#define N_NODES    100000
#define N_EDGES    1600000
#define NUM_REL    4
#define NUM_GRAPHS 256

constexpr int NR       = N_NODES * NUM_REL;   // 400000 segments
constexpr int NB       = (NR + 255) / 256;    // 1563 scan blocks
constexpr int SB_ITEMS = (NB + 255) / 256;    // 7 items/thread in scanB

struct alignas(4) h2 { _Float16 x, y; };

// ---- monotonic float<->uint encoding for atomicMax on floats ----
__device__ __forceinline__ unsigned fenc(float f) {
    unsigned u = __float_as_uint(f);
    return (u & 0x80000000u) ? ~u : (u | 0x80000000u);
}
__device__ __forceinline__ float fdec(unsigned e) {
    return __uint_as_float((e & 0x80000000u) ? (e ^ 0x80000000u) : ~e);
}

__global__ void init_kernel(int* __restrict__ cnt, unsigned* __restrict__ pool) {
    int i = blockIdx.x * blockDim.x + threadIdx.x;
    if (i < NR) cnt[i] = 0;
    if (i < NUM_GRAPHS * 64) pool[i] = fenc(-INFINITY);
}

// convert fp32 features to fp16 storage
__global__ void convert_kernel(const float* __restrict__ xin, _Float16* __restrict__ xout,
                               int n) {
    int i = blockIdx.x * 256 + threadIdx.x;
    if (i < n) xout[i] = (_Float16)xin[i];
}

// count edges per (dst, rel) segment
__global__ void count_kernel(const int* __restrict__ dst, const int* __restrict__ etype,
                             int* __restrict__ cnt) {
    int e = blockIdx.x * 256 + threadIdx.x;
    if (e >= N_EDGES) return;
    atomicAdd(cnt + dst[e] * NUM_REL + etype[e], 1);
}

// per-block inclusive scan of cnt -> incl; block totals -> bsums
__global__ void scanA_kernel(const int* __restrict__ cnt, int* __restrict__ incl,
                             int* __restrict__ bsums) {
    __shared__ int sd[256];
    int t = threadIdx.x;
    int idx = blockIdx.x * 256 + t;
    sd[t] = (idx < NR) ? cnt[idx] : 0;
    __syncthreads();
#pragma unroll
    for (int off = 1; off < 256; off <<= 1) {
        int a = (t >= off) ? sd[t - off] : 0;
        __syncthreads();
        sd[t] += a;
        __syncthreads();
    }
    if (idx < NR) incl[idx] = sd[t];
    if (t == 255) bsums[blockIdx.x] = sd[255];
}

// single-block exclusive scan of the block sums
__global__ void scanB_kernel(const int* __restrict__ bsums, int* __restrict__ boffs) {
    __shared__ int sd[256];
    int t = threadIdx.x;
    int pre[SB_ITEMS];
    int run = 0;
#pragma unroll
    for (int k = 0; k < SB_ITEMS; ++k) {
        int ix = t * SB_ITEMS + k;
        pre[k] = run;
        run += (ix < NB) ? bsums[ix] : 0;
    }
    sd[t] = run;
    __syncthreads();
#pragma unroll
    for (int off = 1; off < 256; off <<= 1) {
        int a = (t >= off) ? sd[t - off] : 0;
        __syncthreads();
        sd[t] += a;
        __syncthreads();
    }
    int excl = sd[t] - run;
#pragma unroll
    for (int k = 0; k < SB_ITEMS; ++k) {
        int ix = t * SB_ITEMS + k;
        if (ix < NB) boffs[ix] = excl + pre[k];
    }
}

// finalize exclusive offsets in place over incl
__global__ void scanC_kernel(const int* __restrict__ cnt, int* __restrict__ offs_inout,
                             const int* __restrict__ boffs) {
    int idx = blockIdx.x * 256 + threadIdx.x;
    if (idx >= NR) return;
    offs_inout[idx] = boffs[idx >> 8] + offs_inout[idx] - cnt[idx];
}

// place src node ids into CSR slots; offs[seg] ends at segment END (= start + cnt)
__global__ void place_kernel(const int* __restrict__ src, const int* __restrict__ dst,
                             const int* __restrict__ etype, int* __restrict__ offs,
                             int* __restrict__ csr) {
    int e = blockIdx.x * 256 + threadIdx.x;
    if (e >= N_EDGES) return;
    int seg = dst[e] * NUM_REL + etype[e];
    int pos = atomicAdd(offs + seg, 1);
    csr[pos] = src[e];
}

// fused per-node layer: gather per-relation means (single pass, fp16x2, 8-way ILP)
// then transform: out = bias + x@root + sum_r mean_r @ W_r ; optional ReLU / max-pool.
// offsets[] holds segment END (start = offsets[seg] - cnt[seg]) after place_kernel.
template<int DIN, int DOUT, bool RELU, bool POOL>
__global__ __launch_bounds__(256)
void layer_kernel(const _Float16* __restrict__ x,
                  const int* __restrict__ csr,
                  const int* __restrict__ offsets,
                  const int* __restrict__ cnt,
                  const float* __restrict__ W,     // [R, DIN, DOUT]
                  const float* __restrict__ root,  // [DIN, DOUT]
                  const float* __restrict__ bias,  // [DOUT]
                  _Float16* __restrict__ hout,     // [N, DOUT] if !POOL
                  const int* __restrict__ batch,
                  unsigned* __restrict__ pool) {
    constexpr int LPS = DIN / 2;     // lanes per segment (8 or 16)
    constexpr int NPB = 64 / LPS;    // nodes per block   (8 or 4)
    __shared__ alignas(8) float mean[NPB][NUM_REL][DIN];
    __shared__ alignas(8) float xrow[NPB][DIN];
    __shared__ float pval[4][64];
    __shared__ int   pg[4];
    __shared__ int   sameflag;

    const int tid = threadIdx.x;
    const h2* x2 = (const h2*)x;

    // ---- gather: all segments of NPB nodes concurrently ----
    {
        const int gseg  = tid / LPS;            // 0 .. NPB*4-1
        const int ip    = tid % LPS;            // channel pair
        const int nsub  = gseg >> 2;
        const int r     = gseg & 3;
        const int n     = blockIdx.x * NPB + nsub;
        const int seg   = n * NUM_REL + r;
        const int len   = cnt[seg];
        const int start = offsets[seg] - len;

        float sx[8], sy[8];
#pragma unroll
        for (int m = 0; m < 8; ++m) { sx[m] = 0.f; sy[m] = 0.f; }
        for (int k = 0; k < len; k += 8) {
            int lim = len - k;                  // >= 1
            int c[8];
#pragma unroll
            for (int m = 0; m < 8; ++m)
                c[m] = csr[start + (m < lim ? k + m : k)];
            h2 u[8];
#pragma unroll
            for (int m = 0; m < 8; ++m)
                u[m] = x2[(size_t)c[m] * LPS + ip];
#pragma unroll
            for (int m = 0; m < 8; ++m)
                if (m < lim) { sx[m] += (float)u[m].x; sy[m] += (float)u[m].y; }
        }
        float fx = ((sx[0] + sx[1]) + (sx[2] + sx[3])) + ((sx[4] + sx[5]) + (sx[6] + sx[7]));
        float fy = ((sy[0] + sy[1]) + (sy[2] + sy[3])) + ((sy[4] + sy[5]) + (sy[6] + sy[7]));
        float inv = 1.0f / fmaxf((float)len, 1.0f);
        *(float2*)&mean[nsub][r][2 * ip] = make_float2(fx * inv, fy * inv);
        if (r == 0) {
            h2 v = x2[(size_t)n * LPS + ip];
            *(float2*)&xrow[nsub][2 * ip] = make_float2((float)v.x, (float)v.y);
        }
    }
    __syncthreads();

    // ---- transform ----
    const int w = tid >> 6, lane = tid & 63;
    if constexpr (DOUT == 64) {                 // one node per wave (NPB == 4)
        const int n = blockIdx.x * NPB + w;
        const int j = lane;
        float acc = 0.f;
#pragma unroll
        for (int i = 0; i < DIN; ++i)
            acc = fmaf(xrow[w][i], root[i * DOUT + j], acc);
#pragma unroll
        for (int r = 0; r < NUM_REL; ++r) {
            const float* Wr = W + r * DIN * DOUT;
            const float* m  = mean[w][r];
#pragma unroll
            for (int i = 0; i < DIN; ++i)
                acc = fmaf(m[i], Wr[i * DOUT + j], acc);
        }
        acc += bias[j];
        // fused max-pool (batch sorted -> block's 4 nodes usually share a graph)
        pval[w][lane] = acc;
        if (lane == 0) pg[w] = batch[n];
        __syncthreads();
        if (tid == 0)
            sameflag = (pg[0] == pg[1]) && (pg[0] == pg[2]) && (pg[0] == pg[3]);
        __syncthreads();
        if (sameflag) {
            if (w == 0) {
                float m0 = fmaxf(fmaxf(pval[0][lane], pval[1][lane]),
                                 fmaxf(pval[2][lane], pval[3][lane]));
                atomicMax(pool + pg[0] * 64 + lane, fenc(m0));
            }
        } else {
            atomicMax(pool + pg[w] * 64 + lane, fenc(pval[w][lane]));
        }
    } else if constexpr (DOUT == 32) {          // two nodes per wave (NPB == 8)
        const int nsub = w * 2 + (lane >> 5);
        const int n = blockIdx.x * NPB + nsub;
        const int j = lane & 31;
        float acc = 0.f;
#pragma unroll
        for (int i = 0; i < DIN; ++i)
            acc = fmaf(xrow[nsub][i], root[i * DOUT + j], acc);
#pragma unroll
        for (int r = 0; r < NUM_REL; ++r) {
            const float* Wr = W + r * DIN * DOUT;
            const float* m  = mean[nsub][r];
#pragma unroll
            for (int i = 0; i < DIN; ++i)
                acc = fmaf(m[i], Wr[i * DOUT + j], acc);
        }
        acc += bias[j];
        float v = RELU ? fmaxf(acc, 0.f) : acc;
        hout[(size_t)n * DOUT + j] = (_Float16)v;
    } else {                                    // DOUT == 16, two nodes per wave (NPB == 8)
        const int nsub = w * 2 + (lane >> 5);
        const int n = blockIdx.x * NPB + nsub;
        const int lane32 = lane & 31;
        const int j = lane32 & 15;
        const int q = lane32 >> 4;
        float acc = 0.f;
        for (int t = q; t < NUM_REL + 1; t += 2) {
            if (t == 0) {
#pragma unroll
                for (int i = 0; i < DIN; ++i)
                    acc = fmaf(xrow[nsub][i], root[i * DOUT + j], acc);
            } else {
                const int r = t - 1;
                const float* Wr = W + r * DIN * DOUT;
                const float* m  = mean[nsub][r];
#pragma unroll
                for (int i = 0; i < DIN; ++i)
                    acc = fmaf(m[i], Wr[i * DOUT + j], acc);
            }
        }
        acc += __shfl_xor(acc, 16);
        acc += bias[j];
        if (q == 0) {
            float v = RELU ? fmaxf(acc, 0.f) : acc;
            hout[(size_t)n * DOUT + j] = (_Float16)v;
        }
    }
}

__global__ void decode_kernel(const unsigned* __restrict__ pool, float* __restrict__ out) {
    int i = blockIdx.x * blockDim.x + threadIdx.x;
    if (i < NUM_GRAPHS * 64) out[i] = fdec(pool[i]);
}

extern "C" void kernel_launch(void* const* d_in, const int* in_sizes, int n_in,
                              void* d_out, int out_size, void* d_ws, size_t ws_size,
                              hipStream_t stream) {
    const float* x     = (const float*)d_in[0];
    const int*   ei    = (const int*)d_in[1];
    const int*   etype = (const int*)d_in[2];
    const int*   batch = (const int*)d_in[3];
    const float* W1 = (const float*)d_in[4],  *root1 = (const float*)d_in[5],  *b1 = (const float*)d_in[6];
    const float* W2 = (const float*)d_in[7],  *root2 = (const float*)d_in[8],  *b2 = (const float*)d_in[9];
    const float* W3 = (const float*)d_in[10], *root3 = (const float*)d_in[11], *b3 = (const float*)d_in[12];
    float* out = (float*)d_out;

    const int* src = ei;
    const int* dst = ei + N_EDGES;

    // workspace layout, ~23 MB total
    int*       cnt   = (int*)d_ws;                   // NR
    int*       offs  = cnt + NR;                     // NR
    int*       bsums = offs + NR;                    // 2048
    int*       boffs = bsums + 2048;                 // 2048
    int*       csr   = boffs + 2048;                 // N_EDGES
    _Float16*  xh    = (_Float16*)(csr + N_EDGES);   // N*16
    _Float16*  h1    = xh + (size_t)N_NODES * 16;    // N*16
    _Float16*  h2    = h1 + (size_t)N_NODES * 16;    // N*32
    unsigned*  pool  = (unsigned*)(h2 + (size_t)N_NODES * 32); // 256*64

    const int BT = 256;
    const int gE = (N_EDGES + BT - 1) / BT;
    const int gI = (NR + BT - 1) / BT;

    init_kernel<<<gI, BT, 0, stream>>>(cnt, pool);
    convert_kernel<<<(N_NODES * 16 + BT - 1) / BT, BT, 0, stream>>>(x, xh, N_NODES * 16);
    count_kernel<<<gE, BT, 0, stream>>>(dst, etype, cnt);
    scanA_kernel<<<NB, BT, 0, stream>>>(cnt, offs, bsums);
    scanB_kernel<<<1, BT, 0, stream>>>(bsums, boffs);
    scanC_kernel<<<gI, BT, 0, stream>>>(cnt, offs, boffs);
    place_kernel<<<gE, BT, 0, stream>>>(src, dst, etype, offs, csr);

    layer_kernel<16, 16, true,  false><<<N_NODES / 8, BT, 0, stream>>>(
        xh, csr, offs, cnt, W1, root1, b1, h1, batch, pool);
    layer_kernel<16, 32, true,  false><<<N_NODES / 8, BT, 0, stream>>>(
        h1, csr, offs, cnt, W2, root2, b2, h2, batch, pool);
    layer_kernel<32, 64, false, true ><<<N_NODES / 4, BT, 0, stream>>>(
        h2, csr, offs, cnt, W3, root3, b3, nullptr, batch, pool);

    decode_kernel<<<(NUM_GRAPHS * 64 + BT - 1) / BT, BT, 0, stream>>>(pool, out);
}

// Round 7
// 422.652 us; speedup vs baseline: 1.1472x; 1.0998x over previous
//
#include <hip/hip_runtime.h>

#define N_NODES    100000
#define N_EDGES    1600000
#define NUM_REL    4
#define NUM_GRAPHS 256

constexpr int NR       = N_NODES * NUM_REL;   // 400000 segments
constexpr int NB       = (NR + 255) / 256;    // 1563 scan blocks
constexpr int SB_ITEMS = (NB + 255) / 256;    // 7 items/thread in scanB

typedef _Float16 half4v __attribute__((ext_vector_type(4)));  // 8B
typedef _Float16 half8v __attribute__((ext_vector_type(8)));  // 16B

// ---- monotonic float<->uint encoding for atomicMax on floats ----
__device__ __forceinline__ unsigned fenc(float f) {
    unsigned u = __float_as_uint(f);
    return (u & 0x80000000u) ? ~u : (u | 0x80000000u);
}
__device__ __forceinline__ float fdec(unsigned e) {
    return __uint_as_float((e & 0x80000000u) ? (e ^ 0x80000000u) : ~e);
}

__global__ void init_kernel(int* __restrict__ cnt, unsigned* __restrict__ pool) {
    int i = blockIdx.x * blockDim.x + threadIdx.x;
    if (i < NR) cnt[i] = 0;
    if (i < NUM_GRAPHS * 64) pool[i] = fenc(-INFINITY);
}

// convert fp32 features to fp16 storage
__global__ void convert_kernel(const float* __restrict__ xin, _Float16* __restrict__ xout,
                               int n) {
    int i = blockIdx.x * 256 + threadIdx.x;
    if (i < n) xout[i] = (_Float16)xin[i];
}

// count edges per (dst, rel) segment
__global__ void count_kernel(const int* __restrict__ dst, const int* __restrict__ etype,
                             int* __restrict__ cnt) {
    int e = blockIdx.x * 256 + threadIdx.x;
    if (e >= N_EDGES) return;
    atomicAdd(cnt + dst[e] * NUM_REL + etype[e], 1);
}

// per-block inclusive scan of cnt -> incl; block totals -> bsums
__global__ void scanA_kernel(const int* __restrict__ cnt, int* __restrict__ incl,
                             int* __restrict__ bsums) {
    __shared__ int sd[256];
    int t = threadIdx.x;
    int idx = blockIdx.x * 256 + t;
    sd[t] = (idx < NR) ? cnt[idx] : 0;
    __syncthreads();
#pragma unroll
    for (int off = 1; off < 256; off <<= 1) {
        int a = (t >= off) ? sd[t - off] : 0;
        __syncthreads();
        sd[t] += a;
        __syncthreads();
    }
    if (idx < NR) incl[idx] = sd[t];
    if (t == 255) bsums[blockIdx.x] = sd[255];
}

// single-block exclusive scan of the block sums
__global__ void scanB_kernel(const int* __restrict__ bsums, int* __restrict__ boffs) {
    __shared__ int sd[256];
    int t = threadIdx.x;
    int pre[SB_ITEMS];
    int run = 0;
#pragma unroll
    for (int k = 0; k < SB_ITEMS; ++k) {
        int ix = t * SB_ITEMS + k;
        pre[k] = run;
        run += (ix < NB) ? bsums[ix] : 0;
    }
    sd[t] = run;
    __syncthreads();
#pragma unroll
    for (int off = 1; off < 256; off <<= 1) {
        int a = (t >= off) ? sd[t - off] : 0;
        __syncthreads();
        sd[t] += a;
        __syncthreads();
    }
    int excl = sd[t] - run;
#pragma unroll
    for (int k = 0; k < SB_ITEMS; ++k) {
        int ix = t * SB_ITEMS + k;
        if (ix < NB) boffs[ix] = excl + pre[k];
    }
}

// finalize exclusive offsets in place over incl
__global__ void scanC_kernel(const int* __restrict__ cnt, int* __restrict__ offs_inout,
                             const int* __restrict__ boffs) {
    int idx = blockIdx.x * 256 + threadIdx.x;
    if (idx >= NR) return;
    offs_inout[idx] = boffs[idx >> 8] + offs_inout[idx] - cnt[idx];
}

// place src node ids into CSR slots; offs[seg] ends at segment END (= start + cnt)
__global__ void place_kernel(const int* __restrict__ src, const int* __restrict__ dst,
                             const int* __restrict__ etype, int* __restrict__ offs,
                             int* __restrict__ csr) {
    int e = blockIdx.x * 256 + threadIdx.x;
    if (e >= N_EDGES) return;
    int seg = dst[e] * NUM_REL + etype[e];
    int pos = atomicAdd(offs + seg, 1);
    csr[pos] = src[e];
}

// fused per-node layer.
// Gather: 4 lanes per (node,rel) segment, each lane loads DIN/4 fp16 channels per
// edge as one 8B/16B vector load -> 16 segments in flight per wave (high MLP).
// Transform: 16 nodes/block, no cross-lane reduction needed for any DOUT.
// offsets[] holds segment END (start = offsets[seg] - cnt[seg]) after place_kernel.
template<int DIN, int DOUT, bool RELU, bool POOL>
__global__ __launch_bounds__(256)
void layer_kernel(const _Float16* __restrict__ x,
                  const int* __restrict__ csr,
                  const int* __restrict__ offsets,
                  const int* __restrict__ cnt,
                  const float* __restrict__ W,     // [R, DIN, DOUT]
                  const float* __restrict__ root,  // [DIN, DOUT]
                  const float* __restrict__ bias,  // [DOUT]
                  _Float16* __restrict__ hout,     // [N, DOUT] if !POOL
                  const int* __restrict__ batch,
                  unsigned* __restrict__ pool) {
    constexpr int NPB = 16;          // nodes per block (64 segments = 64 groups of 4 lanes)
    constexpr int CPL = DIN / 4;     // channels per lane (4 or 8)
    using VecT = typename std::conditional<CPL == 8, half8v, half4v>::type;

    __shared__ alignas(16) float mean[NPB][NUM_REL][DIN];
    __shared__ alignas(16) float xrow[NPB][DIN];
    __shared__ float pval[POOL ? NPB : 1][64];
    __shared__ int   pg[NPB];

    const int tid = threadIdx.x;

    // ---- gather ----
    {
        const int g    = tid >> 2;          // segment group 0..63
        const int q    = tid & 3;           // lane within group
        const int nsub = g >> 2;
        const int r    = g & 3;
        const int n    = blockIdx.x * NPB + nsub;
        const int seg  = n * NUM_REL + r;
        const int len  = cnt[seg];
        const int start = offsets[seg] - len;
        const VecT* xv = (const VecT*)x;    // row = 4 VecT

        float acc[CPL];
#pragma unroll
        for (int ch = 0; ch < CPL; ++ch) acc[ch] = 0.f;

        for (int k = 0; k < len; k += 8) {
            int lim = len - k;              // >= 1
            int c[8];
#pragma unroll
            for (int m = 0; m < 8; ++m)
                c[m] = csr[start + (m < lim ? k + m : k)];
            VecT u[8];
#pragma unroll
            for (int m = 0; m < 8; ++m)
                u[m] = xv[(size_t)c[m] * 4 + q];
#pragma unroll
            for (int m = 0; m < 8; ++m)
                if (m < lim) {
#pragma unroll
                    for (int ch = 0; ch < CPL; ++ch) acc[ch] += (float)u[m][ch];
                }
        }
        float inv = 1.0f / fmaxf((float)len, 1.0f);
#pragma unroll
        for (int ch = 0; ch < CPL; ch += 4)
            *(float4*)&mean[nsub][r][q * CPL + ch] =
                make_float4(acc[ch] * inv, acc[ch + 1] * inv,
                            acc[ch + 2] * inv, acc[ch + 3] * inv);
        if (r == 0) {
            VecT v = xv[(size_t)n * 4 + q];
#pragma unroll
            for (int ch = 0; ch < CPL; ch += 4)
                *(float4*)&xrow[nsub][q * CPL + ch] =
                    make_float4((float)v[ch], (float)v[ch + 1],
                                (float)v[ch + 2], (float)v[ch + 3]);
        }
        if constexpr (POOL) {
            if (tid < NPB) pg[tid] = batch[blockIdx.x * NPB + tid];
        }
    }
    __syncthreads();

    // ---- transform: wave w handles nodes 4w..4w+3 ----
    {
        const int w = tid >> 6, lane = tid & 63;
        constexpr int NPW    = 64 / DOUT;   // nodes concurrent per wave (4,2,1)
        constexpr int PASSES = 4 / NPW;
        const int j = lane % DOUT;
#pragma unroll
        for (int p = 0; p < PASSES; ++p) {
            const int nsub = w * 4 + p * NPW + lane / DOUT;
            float acc = 0.f;
#pragma unroll
            for (int i = 0; i < DIN; ++i)
                acc = fmaf(xrow[nsub][i], root[i * DOUT + j], acc);
#pragma unroll
            for (int r = 0; r < NUM_REL; ++r) {
                const float* Wr = W + r * DIN * DOUT;
                const float* m  = mean[nsub][r];
#pragma unroll
                for (int i = 0; i < DIN; ++i)
                    acc = fmaf(m[i], Wr[i * DOUT + j], acc);
            }
            acc += bias[j];
            if constexpr (POOL) {
                pval[nsub][j] = acc;
            } else {
                const int n = blockIdx.x * NPB + nsub;
                float v = RELU ? fmaxf(acc, 0.f) : acc;
                hout[(size_t)n * DOUT + j] = (_Float16)v;
            }
        }
    }

    // ---- fused max-pool over the block's 16 (sorted-batch) nodes ----
    if constexpr (POOL) {
        __syncthreads();
        if (tid < 64) {
            const int j = tid;
            float m = pval[0][j];
            int g0 = pg[0];
#pragma unroll
            for (int i = 1; i < NPB; ++i) {
                if (pg[i] == g0) {
                    m = fmaxf(m, pval[i][j]);
                } else {
                    atomicMax(pool + g0 * 64 + j, fenc(m));
                    g0 = pg[i];
                    m = pval[i][j];
                }
            }
            atomicMax(pool + g0 * 64 + j, fenc(m));
        }
    }
}

__global__ void decode_kernel(const unsigned* __restrict__ pool, float* __restrict__ out) {
    int i = blockIdx.x * blockDim.x + threadIdx.x;
    if (i < NUM_GRAPHS * 64) out[i] = fdec(pool[i]);
}

extern "C" void kernel_launch(void* const* d_in, const int* in_sizes, int n_in,
                              void* d_out, int out_size, void* d_ws, size_t ws_size,
                              hipStream_t stream) {
    const float* x     = (const float*)d_in[0];
    const int*   ei    = (const int*)d_in[1];
    const int*   etype = (const int*)d_in[2];
    const int*   batch = (const int*)d_in[3];
    const float* W1 = (const float*)d_in[4],  *root1 = (const float*)d_in[5],  *b1 = (const float*)d_in[6];
    const float* W2 = (const float*)d_in[7],  *root2 = (const float*)d_in[8],  *b2 = (const float*)d_in[9];
    const float* W3 = (const float*)d_in[10], *root3 = (const float*)d_in[11], *b3 = (const float*)d_in[12];
    float* out = (float*)d_out;

    const int* src = ei;
    const int* dst = ei + N_EDGES;

    // workspace layout, ~23 MB total (all sections 16B-aligned)
    int*       cnt   = (int*)d_ws;                   // NR
    int*       offs  = cnt + NR;                     // NR
    int*       bsums = offs + NR;                    // 2048
    int*       boffs = bsums + 2048;                 // 2048
    int*       csr   = boffs + 2048;                 // N_EDGES
    _Float16*  xh    = (_Float16*)(csr + N_EDGES);   // N*16
    _Float16*  h1    = xh + (size_t)N_NODES * 16;    // N*16
    _Float16*  h2    = h1 + (size_t)N_NODES * 16;    // N*32
    unsigned*  pool  = (unsigned*)(h2 + (size_t)N_NODES * 32); // 256*64

    const int BT = 256;
    const int gE = (N_EDGES + BT - 1) / BT;
    const int gI = (NR + BT - 1) / BT;

    init_kernel<<<gI, BT, 0, stream>>>(cnt, pool);
    convert_kernel<<<(N_NODES * 16 + BT - 1) / BT, BT, 0, stream>>>(x, xh, N_NODES * 16);
    count_kernel<<<gE, BT, 0, stream>>>(dst, etype, cnt);
    scanA_kernel<<<NB, BT, 0, stream>>>(cnt, offs, bsums);
    scanB_kernel<<<1, BT, 0, stream>>>(bsums, boffs);
    scanC_kernel<<<gI, BT, 0, stream>>>(cnt, offs, boffs);
    place_kernel<<<gE, BT, 0, stream>>>(src, dst, etype, offs, csr);

    layer_kernel<16, 16, true,  false><<<N_NODES / 16, BT, 0, stream>>>(
        xh, csr, offs, cnt, W1, root1, b1, h1, batch, pool);
    layer_kernel<16, 32, true,  false><<<N_NODES / 16, BT, 0, stream>>>(
        h1, csr, offs, cnt, W2, root2, b2, h2, batch, pool);
    layer_kernel<32, 64, false, true ><<<N_NODES / 16, BT, 0, stream>>>(
        h2, csr, offs, cnt, W3, root3, b3, nullptr, batch, pool);

    decode_kernel<<<(NUM_GRAPHS * 64 + BT - 1) / BT, BT, 0, stream>>>(pool, out);
}

// Round 8
// 323.824 us; speedup vs baseline: 1.4973x; 1.3052x over previous
//
#include <hip/hip_runtime.h>

#define N_NODES    100000
#define N_EDGES    1600000
#define NUM_REL    4
#define NUM_GRAPHS 256

constexpr int NR       = N_NODES * NUM_REL;   // 400000 segments
constexpr int NB       = (NR + 255) / 256;    // 1563 scan blocks
constexpr int SB_ITEMS = (NB + 255) / 256;    // 7 items/thread in scanB

typedef _Float16 half4v __attribute__((ext_vector_type(4)));  // 8B
typedef _Float16 half8v __attribute__((ext_vector_type(8)));  // 16B
typedef float    f32x4  __attribute__((ext_vector_type(4)));

// ---- monotonic float<->uint encoding for atomicMax on floats ----
__device__ __forceinline__ unsigned fenc(float f) {
    unsigned u = __float_as_uint(f);
    return (u & 0x80000000u) ? ~u : (u | 0x80000000u);
}
__device__ __forceinline__ float fdec(unsigned e) {
    return __uint_as_float((e & 0x80000000u) ? (e ^ 0x80000000u) : ~e);
}

__global__ void init_kernel(int* __restrict__ cnt, unsigned* __restrict__ pool) {
    int i = blockIdx.x * blockDim.x + threadIdx.x;
    if (i < NR) cnt[i] = 0;
    if (i < NUM_GRAPHS * 64) pool[i] = fenc(-INFINITY);
}

__global__ void convert_kernel(const float* __restrict__ xin, _Float16* __restrict__ xout,
                               int n) {
    int i = blockIdx.x * 256 + threadIdx.x;
    if (i < n) xout[i] = (_Float16)xin[i];
}

// build fp16 weight stack, transposed: Bt[j][kk], kk = [root rows; W0..W3 rows]
template<int DIN, int DOUT, int SK>
__global__ void bstack_kernel(const float* __restrict__ W, const float* __restrict__ root,
                              _Float16* __restrict__ Bt) {
    int i = blockIdx.x * 256 + threadIdx.x;
    if (i >= DOUT * SK) return;
    int j = i / SK, kk = i % SK;
    float v;
    if (kk < DIN)               v = root[kk * DOUT + j];
    else if (kk < 5 * DIN)      v = W[(kk - DIN) * DOUT + j];  // [R,DIN,DOUT] flat
    else                        v = 0.f;                        // pad
    Bt[j * SK + kk] = (_Float16)v;
}

__global__ void count_kernel(const int* __restrict__ dst, const int* __restrict__ etype,
                             int* __restrict__ cnt) {
    int e = blockIdx.x * 256 + threadIdx.x;
    if (e >= N_EDGES) return;
    atomicAdd(cnt + dst[e] * NUM_REL + etype[e], 1);
}

__global__ void scanA_kernel(const int* __restrict__ cnt, int* __restrict__ incl,
                             int* __restrict__ bsums) {
    __shared__ int sd[256];
    int t = threadIdx.x;
    int idx = blockIdx.x * 256 + t;
    sd[t] = (idx < NR) ? cnt[idx] : 0;
    __syncthreads();
#pragma unroll
    for (int off = 1; off < 256; off <<= 1) {
        int a = (t >= off) ? sd[t - off] : 0;
        __syncthreads();
        sd[t] += a;
        __syncthreads();
    }
    if (idx < NR) incl[idx] = sd[t];
    if (t == 255) bsums[blockIdx.x] = sd[255];
}

__global__ void scanB_kernel(const int* __restrict__ bsums, int* __restrict__ boffs) {
    __shared__ int sd[256];
    int t = threadIdx.x;
    int pre[SB_ITEMS];
    int run = 0;
#pragma unroll
    for (int k = 0; k < SB_ITEMS; ++k) {
        int ix = t * SB_ITEMS + k;
        pre[k] = run;
        run += (ix < NB) ? bsums[ix] : 0;
    }
    sd[t] = run;
    __syncthreads();
#pragma unroll
    for (int off = 1; off < 256; off <<= 1) {
        int a = (t >= off) ? sd[t - off] : 0;
        __syncthreads();
        sd[t] += a;
        __syncthreads();
    }
    int excl = sd[t] - run;
#pragma unroll
    for (int k = 0; k < SB_ITEMS; ++k) {
        int ix = t * SB_ITEMS + k;
        if (ix < NB) boffs[ix] = excl + pre[k];
    }
}

__global__ void scanC_kernel(const int* __restrict__ cnt, int* __restrict__ offs_inout,
                             const int* __restrict__ boffs) {
    int idx = blockIdx.x * 256 + threadIdx.x;
    if (idx >= NR) return;
    offs_inout[idx] = boffs[idx >> 8] + offs_inout[idx] - cnt[idx];
}

__global__ void place_kernel(const int* __restrict__ src, const int* __restrict__ dst,
                             const int* __restrict__ etype, int* __restrict__ offs,
                             int* __restrict__ csr) {
    int e = blockIdx.x * 256 + threadIdx.x;
    if (e >= N_EDGES) return;
    int seg = dst[e] * NUM_REL + etype[e];
    int pos = atomicAdd(offs + seg, 1);
    csr[pos] = src[e];
}

// gather-only: pre[n] = [ x_n (DIN) | mean_r0 .. mean_r3 (DIN each) | pad ]
// 4 lanes per (node,rel) segment; 16 nodes per block; no LDS, no barriers.
template<int DIN, int SK>
__global__ __launch_bounds__(256)
void gather_kernel(const _Float16* __restrict__ x,
                   const int* __restrict__ csr,
                   const int* __restrict__ offsets,   // segment ENDs
                   const int* __restrict__ cnt,
                   _Float16* __restrict__ pre) {
    constexpr int NPB = 16;
    constexpr int CPL = DIN / 4;     // fp16 channels per lane (4 or 8)
    using VecT = typename std::conditional<CPL == 8, half8v, half4v>::type;

    const int tid = threadIdx.x;
    const int g    = tid >> 2;       // 0..63 segment group
    const int q    = tid & 3;
    const int nsub = g >> 2;
    const int r    = g & 3;
    const int n    = blockIdx.x * NPB + nsub;
    const int seg  = n * NUM_REL + r;
    const int len  = cnt[seg];
    const int start = offsets[seg] - len;
    const VecT* xv = (const VecT*)x;     // row = 4 VecT

    float acc[CPL];
#pragma unroll
    for (int ch = 0; ch < CPL; ++ch) acc[ch] = 0.f;

    for (int k = 0; k < len; k += 8) {
        int lim = len - k;               // >= 1
        int c[8];
#pragma unroll
        for (int m = 0; m < 8; ++m)
            c[m] = csr[start + (m < lim ? k + m : k)];
        VecT u[8];
#pragma unroll
        for (int m = 0; m < 8; ++m)
            u[m] = xv[(size_t)c[m] * 4 + q];
#pragma unroll
        for (int m = 0; m < 8; ++m)
            if (m < lim) {
#pragma unroll
                for (int ch = 0; ch < CPL; ++ch) acc[ch] += (float)u[m][ch];
            }
    }
    float inv = 1.0f / fmaxf((float)len, 1.0f);
    VecT hv;
#pragma unroll
    for (int ch = 0; ch < CPL; ++ch) hv[ch] = (_Float16)(acc[ch] * inv);
    *(VecT*)&pre[(size_t)n * SK + DIN + r * DIN + q * CPL] = hv;
    if (r == 0)
        *(VecT*)&pre[(size_t)n * SK + q * CPL] = xv[(size_t)n * 4 + q];
    if constexpr (SK > 5 * DIN) {
        // zero the K-pad (SK - 5*DIN = 16 fp16 = 2x16B per node)
        if (tid < NPB * 2) {
            int n2 = blockIdx.x * NPB + (tid >> 1);
            *(uint4*)&pre[(size_t)n2 * SK + 5 * DIN + (tid & 1) * 8] = uint4{0, 0, 0, 0};
        }
    }
}

// MFMA GEMM: hout[N, DOUT] = relu(pre[N, K] @ Bstack[K, DOUT] + bias)
// fragment mapping (m89-verified): A: lane=[l&15][(l>>4)*8+u]; B: [k][l&15]; D: [(l>>4)*4+reg][l&15]
template<int K, int DOUT, bool RELU>
__global__ __launch_bounds__(256)
void gemm_kernel(const _Float16* __restrict__ pre,
                 const _Float16* __restrict__ Bt,    // [DOUT][K]
                 const float* __restrict__ bias,     // [DOUT]
                 _Float16* __restrict__ hout) {
    constexpr int NT = DOUT / 16;
    constexpr int KS = K / 32;
    constexpr int KP = K + 8;                        // LDS row pad: kill bank conflicts
    __shared__ _Float16 sB[DOUT * KP];
    for (int i = threadIdx.x; i < DOUT * K; i += 256) {
        int j = i / K, kk = i % K;
        sB[j * KP + kk] = Bt[i];
    }
    __syncthreads();

    const int w = threadIdx.x >> 6, lane = threadIdx.x & 63;
    const int m0 = (blockIdx.x * 4 + w) * 16;
    if (m0 >= N_NODES) return;
    const int lo16 = lane & 15, hi = lane >> 4;

    f32x4 acc[NT];
#pragma unroll
    for (int nt = 0; nt < NT; ++nt) acc[nt] = f32x4{0.f, 0.f, 0.f, 0.f};

#pragma unroll
    for (int ks = 0; ks < KS; ++ks) {
        half8v a = *(const half8v*)&pre[(size_t)(m0 + lo16) * K + ks * 32 + hi * 8];
#pragma unroll
        for (int nt = 0; nt < NT; ++nt) {
            half8v b = *(const half8v*)&sB[(nt * 16 + lo16) * KP + ks * 32 + hi * 8];
            acc[nt] = __builtin_amdgcn_mfma_f32_16x16x32_f16(a, b, acc[nt], 0, 0, 0);
        }
    }
#pragma unroll
    for (int nt = 0; nt < NT; ++nt) {
        float bj = bias[nt * 16 + lo16];
#pragma unroll
        for (int reg = 0; reg < 4; ++reg) {
            float v = acc[nt][reg] + bj;
            if (RELU) v = fmaxf(v, 0.f);
            hout[(size_t)(m0 + hi * 4 + reg) * DOUT + nt * 16 + lo16] = (_Float16)v;
        }
    }
}

// max-pool over sorted batch: each thread scans 64 nodes for one channel
__global__ __launch_bounds__(256)
void pool_kernel(const _Float16* __restrict__ h3, const int* __restrict__ batch,
                 unsigned* __restrict__ pool) {
    const int j = threadIdx.x & 63;
    const int grp = threadIdx.x >> 6;
    const int n0 = blockIdx.x * 256 + grp * 64;
    if (n0 >= N_NODES) return;
    const int end = min(n0 + 64, N_NODES);
    int g = batch[n0];
    float m = -INFINITY;
    for (int n = n0; n < end; ++n) {
        float v = (float)h3[(size_t)n * 64 + j];
        int bg = batch[n];
        if (bg != g) {
            atomicMax(pool + g * 64 + j, fenc(m));
            g = bg;
            m = v;
        } else {
            m = fmaxf(m, v);
        }
    }
    atomicMax(pool + g * 64 + j, fenc(m));
}

__global__ void decode_kernel(const unsigned* __restrict__ pool, float* __restrict__ out) {
    int i = blockIdx.x * blockDim.x + threadIdx.x;
    if (i < NUM_GRAPHS * 64) out[i] = fdec(pool[i]);
}

extern "C" void kernel_launch(void* const* d_in, const int* in_sizes, int n_in,
                              void* d_out, int out_size, void* d_ws, size_t ws_size,
                              hipStream_t stream) {
    const float* x     = (const float*)d_in[0];
    const int*   ei    = (const int*)d_in[1];
    const int*   etype = (const int*)d_in[2];
    const int*   batch = (const int*)d_in[3];
    const float* W1 = (const float*)d_in[4],  *root1 = (const float*)d_in[5],  *b1 = (const float*)d_in[6];
    const float* W2 = (const float*)d_in[7],  *root2 = (const float*)d_in[8],  *b2 = (const float*)d_in[9];
    const float* W3 = (const float*)d_in[10], *root3 = (const float*)d_in[11], *b3 = (const float*)d_in[12];
    float* out = (float*)d_out;

    const int* src = ei;
    const int* dst = ei + N_EDGES;

    // workspace layout (~67.5 MB), all sections 16B aligned
    int*       cnt   = (int*)d_ws;                     // NR
    int*       offs  = cnt + NR;                       // NR
    int*       bsums = offs + NR;                      // 2048
    int*       boffs = bsums + 2048;                   // 2048
    int*       csr   = boffs + 2048;                   // N_EDGES
    _Float16*  xh    = (_Float16*)(csr + N_EDGES);     // N*16
    _Float16*  h1    = xh + (size_t)N_NODES * 16;      // N*16
    _Float16*  h2    = h1 + (size_t)N_NODES * 16;      // N*32
    _Float16*  h3    = h2 + (size_t)N_NODES * 32;      // N*64
    _Float16*  pre   = h3 + (size_t)N_NODES * 64;      // N*160 (max)
    _Float16*  Bt1   = pre + (size_t)N_NODES * 160;    // 16*96
    _Float16*  Bt2   = Bt1 + 16 * 96;                  // 32*96
    _Float16*  Bt3   = Bt2 + 32 * 96;                  // 64*160
    unsigned*  pool  = (unsigned*)(Bt3 + 64 * 160);    // 256*64

    const int BT = 256;
    const int gE = (N_EDGES + BT - 1) / BT;
    const int gI = (NR + BT - 1) / BT;
    const int gG = N_NODES / 16;         // gather blocks
    const int gM = (N_NODES / 16 + 3) / 4;  // gemm blocks (4 M-tiles each)

    init_kernel<<<gI, BT, 0, stream>>>(cnt, pool);
    convert_kernel<<<(N_NODES * 16 + BT - 1) / BT, BT, 0, stream>>>(x, xh, N_NODES * 16);
    bstack_kernel<16, 16, 96><<<(16 * 96 + BT - 1) / BT, BT, 0, stream>>>(W1, root1, Bt1);
    bstack_kernel<16, 32, 96><<<(32 * 96 + BT - 1) / BT, BT, 0, stream>>>(W2, root2, Bt2);
    bstack_kernel<32, 64, 160><<<(64 * 160 + BT - 1) / BT, BT, 0, stream>>>(W3, root3, Bt3);

    count_kernel<<<gE, BT, 0, stream>>>(dst, etype, cnt);
    scanA_kernel<<<NB, BT, 0, stream>>>(cnt, offs, bsums);
    scanB_kernel<<<1, BT, 0, stream>>>(bsums, boffs);
    scanC_kernel<<<gI, BT, 0, stream>>>(cnt, offs, boffs);
    place_kernel<<<gE, BT, 0, stream>>>(src, dst, etype, offs, csr);

    gather_kernel<16, 96><<<gG, BT, 0, stream>>>(xh, csr, offs, cnt, pre);
    gemm_kernel<96, 16, true><<<gM, BT, 0, stream>>>(pre, Bt1, b1, h1);

    gather_kernel<16, 96><<<gG, BT, 0, stream>>>(h1, csr, offs, cnt, pre);
    gemm_kernel<96, 32, true><<<gM, BT, 0, stream>>>(pre, Bt2, b2, h2);

    gather_kernel<32, 160><<<gG, BT, 0, stream>>>(h2, csr, offs, cnt, pre);
    gemm_kernel<160, 64, false><<<gM, BT, 0, stream>>>(pre, Bt3, b3, h3);

    pool_kernel<<<(N_NODES + 255) / 256, BT, 0, stream>>>(h3, batch, pool);
    decode_kernel<<<(NUM_GRAPHS * 64 + BT - 1) / BT, BT, 0, stream>>>(pool, out);
}